// Round 2
// baseline (810.205 us; speedup 1.0000x reference)
//
#include <hip/hip_runtime.h>

// GCN 2-layer: h1 = X@W1 ; agg over edges with symmetric norm ; relu ; @W2 ; agg ; +b
// N = 100000 nodes, E = 1.6M edges (+ self-loops folded into finalize).
// NOTE: harness delivers integer inputs as int32 (edge_index: 2 x E int).

// ---------------- degree ----------------
__global__ void deg_kernel(const int* __restrict__ dst, int E, int* __restrict__ deg) {
    int idx = blockIdx.x * blockDim.x + threadIdx.x;
    int stride = gridDim.x * blockDim.x;
    for (int e = idx; e < E; e += stride) {
        atomicAdd(&deg[dst[e]], 1);
    }
}

// in-place: buffer holds int counts, becomes float rsqrt(deg+1)  (+1 = self-loop)
__global__ void dinv_kernel(float* __restrict__ dinv_io, int N) {
    int idx = blockIdx.x * blockDim.x + threadIdx.x;
    if (idx < N) {
        int d = ((const int*)dinv_io)[idx];
        dinv_io[idx] = rsqrtf((float)d + 1.0f);
    }
}

// ---------------- dense GEMM: out[N,C] = A[N,K] @ W[K,C], W staged in LDS ----------------
template <int K, int C>
__global__ void gemm_kernel(const float* __restrict__ A, const float* __restrict__ W,
                            float* __restrict__ out, int N) {
    constexpr int ROWS = 256 / C;  // rows per block-iteration
    __shared__ float Wl[K * C];
    for (int i = threadIdx.x; i < K * C / 4; i += blockDim.x) {
        ((float4*)Wl)[i] = ((const float4*)W)[i];
    }
    __syncthreads();
    const int c = threadIdx.x % C;
    const int r = threadIdx.x / C;
    for (int row = blockIdx.x * ROWS + r; row < N; row += gridDim.x * ROWS) {
        const float4* xr = (const float4*)(A + (size_t)row * K);
        float acc = 0.f;
#pragma unroll
        for (int k4 = 0; k4 < K / 4; ++k4) {
            float4 xv = xr[k4];
            acc += xv.x * Wl[(4 * k4 + 0) * C + c];
            acc += xv.y * Wl[(4 * k4 + 1) * C + c];
            acc += xv.z * Wl[(4 * k4 + 2) * C + c];
            acc += xv.w * Wl[(4 * k4 + 3) * C + c];
        }
        out[(size_t)row * C + c] = acc;
    }
}

// ---------------- edge scatter: agg[dst] += h[src] * dinv[src]*dinv[dst] ----------------
// C lanes cooperate on one edge (lane = output column) -> coalesced gather + atomic burst.
template <int C>
__global__ void scatter_kernel(const float* __restrict__ h, const float* __restrict__ dinv,
                               const int* __restrict__ src, const int* __restrict__ dst,
                               float* __restrict__ agg, int E) {
    int gtid = blockIdx.x * blockDim.x + threadIdx.x;
    int lane = gtid % C;
    int e0 = gtid / C;
    int estride = (gridDim.x * blockDim.x) / C;
    for (int e = e0; e < E; e += estride) {
        int s = src[e];
        int d = dst[e];
        float nrm = dinv[s] * dinv[d];
        float v = h[(size_t)s * C + lane] * nrm;
        atomicAdd(&agg[(size_t)d * C + lane], v);
    }
}

// ---------------- finalize: out = agg + h*dinv^2 + b  (self-loop folded in), optional relu
// agg may alias out (in-place).
template <int C, bool RELU>
__global__ void finalize_kernel(const float* agg, const float* __restrict__ h,
                                const float* __restrict__ dinv, const float* __restrict__ b,
                                float* out, int N) {
    int idx = blockIdx.x * blockDim.x + threadIdx.x;  // float4 index
    int total = N * C / 4;
    if (idx >= total) return;
    int i = idx / (C / 4);
    int j4 = idx % (C / 4);
    float di = dinv[i];
    float d2 = di * di;
    float4 a = ((const float4*)agg)[idx];
    float4 hv = ((const float4*)h)[idx];
    float4 bv = ((const float4*)b)[j4];
    float4 r;
    r.x = a.x + hv.x * d2 + bv.x;
    r.y = a.y + hv.y * d2 + bv.y;
    r.z = a.z + hv.z * d2 + bv.z;
    r.w = a.w + hv.w * d2 + bv.w;
    if (RELU) {
        r.x = fmaxf(r.x, 0.f);
        r.y = fmaxf(r.y, 0.f);
        r.z = fmaxf(r.z, 0.f);
        r.w = fmaxf(r.w, 0.f);
    }
    ((float4*)out)[idx] = r;
}

extern "C" void kernel_launch(void* const* d_in, const int* in_sizes, int n_in,
                              void* d_out, int out_size, void* d_ws, size_t ws_size,
                              hipStream_t stream) {
    const float* x = (const float*)d_in[0];
    const int* ei = (const int*)d_in[1];
    const float* W1 = (const float*)d_in[2];
    const float* b1 = (const float*)d_in[3];
    const float* W2 = (const float*)d_in[4];
    const float* b2 = (const float*)d_in[5];

    const int N = in_sizes[0] / 128;   // 100000
    const int E = in_sizes[1] / 2;     // 1600000
    const int* src = ei;
    const int* dst = ei + E;

    // workspace layout (floats)
    float* dinv = (float*)d_ws;                    // N (int during deg pass)
    float* h1 = dinv + ((N + 63) & ~63);           // N*64
    float* agg1 = h1 + (size_t)N * 64;             // N*64, becomes h2 after finalize1
    float* h3 = h1;                                // reuse h1 for layer-2 gemm output (N*32)
    float* out = (float*)d_out;

    // 1) degrees -> dinv
    hipMemsetAsync(dinv, 0, (size_t)N * 4, stream);
    deg_kernel<<<2048, 256, 0, stream>>>(dst, E, (int*)dinv);
    dinv_kernel<<<(N + 255) / 256, 256, 0, stream>>>(dinv, N);

    // 2) h1 = x @ W1
    gemm_kernel<128, 64><<<4096, 256, 0, stream>>>(x, W1, h1, N);

    // 3) scatter layer 1
    hipMemsetAsync(agg1, 0, (size_t)N * 64 * 4, stream);
    scatter_kernel<64><<<2048, 256, 0, stream>>>(h1, dinv, src, dst, agg1, E);

    // 4) finalize1: h2 = relu(agg1 + h1*dinv^2 + b1)   (in place into agg1)
    finalize_kernel<64, true><<<(N * 16 + 255) / 256, 256, 0, stream>>>(agg1, h1, dinv, b1, agg1, N);

    // 5) h3 = h2 @ W2
    gemm_kernel<64, 32><<<4096, 256, 0, stream>>>(agg1, W2, h3, N);

    // 6) scatter layer 2 into d_out
    hipMemsetAsync(out, 0, (size_t)out_size * 4, stream);
    scatter_kernel<32><<<2048, 256, 0, stream>>>(h3, dinv, src, dst, out, E);

    // 7) finalize2: out = out + h3*dinv^2 + b2   (in place)
    finalize_kernel<32, false><<<(N * 8 + 255) / 256, 256, 0, stream>>>(out, h3, dinv, b2, out, N);
}

// Round 3
// 572.539 us; speedup vs baseline: 1.4151x; 1.4151x over previous
//
#include <hip/hip_runtime.h>

// GCN 2-layer via CSR gather (no float atomics).
// Pipeline: deg -> dinv -> scan(offs) -> csr fill ; h1s = (x@W1)*dinv ;
// h2 = relu(dinv*(sum h1s[neigh] + h1s[self]) + b1) ; h3s = (h2@W2)*dinv ;
// out = dinv*(sum h3s[neigh] + h3s[self]) + b2.

// ---------------- degree ----------------
__global__ void deg_kernel(const int* __restrict__ dst, int E, int* __restrict__ deg) {
    int e = blockIdx.x * blockDim.x + threadIdx.x;
    if (e < E) atomicAdd(&deg[dst[e]], 1);
}

__global__ void dinv_kernel(const int* __restrict__ deg, float* __restrict__ dinv, int N) {
    int i = blockIdx.x * blockDim.x + threadIdx.x;
    if (i < N) dinv[i] = rsqrtf((float)deg[i] + 1.0f);  // +1 = self-loop
}

// ---------------- scan: offs = exclusive_scan(deg), offs[N] = E ----------------
__global__ void blocksum_kernel(const int* __restrict__ deg, int N, int* __restrict__ bsum) {
    __shared__ int s[256];
    int i = blockIdx.x * 256 + threadIdx.x;
    s[threadIdx.x] = (i < N) ? deg[i] : 0;
    __syncthreads();
    for (int o = 128; o > 0; o >>= 1) {
        if (threadIdx.x < o) s[threadIdx.x] += s[threadIdx.x + o];
        __syncthreads();
    }
    if (threadIdx.x == 0) bsum[blockIdx.x] = s[0];
}

__global__ void scan_bsum_kernel(int* __restrict__ bsum, int NB) {
    __shared__ int s[1024];
    int t = threadIdx.x;
    int v = (t < NB) ? bsum[t] : 0;
    s[t] = v;
    __syncthreads();
    for (int off = 1; off < 1024; off <<= 1) {
        int x = (t >= off) ? s[t - off] : 0;
        __syncthreads();
        s[t] += x;
        __syncthreads();
    }
    if (t < NB) bsum[t] = s[t] - v;  // exclusive, in place
}

__global__ void offsets_kernel(const int* __restrict__ deg, const int* __restrict__ bsum,
                               int* __restrict__ offs, int N, int E) {
    __shared__ int s[256];
    int t = threadIdx.x;
    int i = blockIdx.x * 256 + t;
    int v = (i < N) ? deg[i] : 0;
    s[t] = v;
    __syncthreads();
    for (int off = 1; off < 256; off <<= 1) {
        int x = (t >= off) ? s[t - off] : 0;
        __syncthreads();
        s[t] += x;
        __syncthreads();
    }
    if (i < N) offs[i] = bsum[blockIdx.x] + s[t] - v;
    if (i == 0) offs[N] = E;
}

__global__ void copy_kernel(const int* __restrict__ a, int* __restrict__ b, int N) {
    int i = blockIdx.x * blockDim.x + threadIdx.x;
    if (i < N) b[i] = a[i];
}

// ---------------- CSR fill: csr_src grouped by dst ----------------
__global__ void fill_kernel(const int* __restrict__ src, const int* __restrict__ dst, int E,
                            int* __restrict__ cursor, int* __restrict__ csr_src) {
    int e = blockIdx.x * blockDim.x + threadIdx.x;
    if (e < E) {
        int pos = atomicAdd(&cursor[dst[e]], 1);
        csr_src[pos] = src[e];
    }
}

// ---------------- dense GEMM with row-scale epilogue: out[r,c] = (A[r,:]@W[:,c]) * dinv[r] ----------------
template <int K, int C>
__global__ void gemm_kernel(const float* __restrict__ A, const float* __restrict__ W,
                            const float* __restrict__ dinv, float* __restrict__ out, int N) {
    constexpr int ROWS = 256 / C;
    __shared__ float Wl[K * C];
    for (int i = threadIdx.x; i < K * C / 4; i += blockDim.x) {
        ((float4*)Wl)[i] = ((const float4*)W)[i];
    }
    __syncthreads();
    const int c = threadIdx.x % C;
    const int r = threadIdx.x / C;
    for (int row = blockIdx.x * ROWS + r; row < N; row += gridDim.x * ROWS) {
        const float4* xr = (const float4*)(A + (size_t)row * K);
        float acc = 0.f;
#pragma unroll
        for (int k4 = 0; k4 < K / 4; ++k4) {
            float4 xv = xr[k4];
            acc += xv.x * Wl[(4 * k4 + 0) * C + c];
            acc += xv.y * Wl[(4 * k4 + 1) * C + c];
            acc += xv.z * Wl[(4 * k4 + 2) * C + c];
            acc += xv.w * Wl[(4 * k4 + 3) * C + c];
        }
        out[(size_t)row * C + c] = acc * dinv[row];
    }
}

// ---------------- gather: out[d] = dinv[d]*(sum_{s in N(d)} hs[s] + hs[d]) + b, optional relu
template <int C, bool RELU>
__global__ void gather_kernel(const float* __restrict__ hs, const float* __restrict__ dinv,
                              const int* __restrict__ offs, const int* __restrict__ csr_src,
                              const float* __restrict__ b, float* __restrict__ out, int N) {
    int gtid = blockIdx.x * blockDim.x + threadIdx.x;
    int lane = gtid % C;
    int d = gtid / C;
    if (d >= N) return;
    float acc = hs[(size_t)d * C + lane];  // self-loop term
    int beg = offs[d];
    int end = offs[d + 1];
    int j = beg;
    for (; j + 1 < end; j += 2) {
        int s0 = csr_src[j];
        int s1 = csr_src[j + 1];
        float v0 = hs[(size_t)s0 * C + lane];
        float v1 = hs[(size_t)s1 * C + lane];
        acc += v0;
        acc += v1;
    }
    if (j < end) acc += hs[(size_t)csr_src[j] * C + lane];
    float r = acc * dinv[d] + b[lane];
    if (RELU) r = fmaxf(r, 0.f);
    out[(size_t)d * C + lane] = r;
}

extern "C" void kernel_launch(void* const* d_in, const int* in_sizes, int n_in,
                              void* d_out, int out_size, void* d_ws, size_t ws_size,
                              hipStream_t stream) {
    const float* x = (const float*)d_in[0];
    const int* ei = (const int*)d_in[1];
    const float* W1 = (const float*)d_in[2];
    const float* b1 = (const float*)d_in[3];
    const float* W2 = (const float*)d_in[4];
    const float* b2 = (const float*)d_in[5];

    const int N = in_sizes[0] / 128;  // 100000
    const int E = in_sizes[1] / 2;    // 1600000
    const int* src = ei;
    const int* dst = ei + E;
    const int NB = (N + 255) / 256;   // 391 scan blocks (must be <= 1024)

    // workspace layout (4-byte elements)
    int* deg = (int*)d_ws;                         // N
    float* dinv = (float*)(deg + NB * 256);        // N
    int* offs = (int*)(dinv + NB * 256);           // N+1 (pad to 256)
    int* cursor = offs + NB * 256 + 256;           // N
    int* bsum = cursor + NB * 256;                 // NB (pad 1024)
    int* csr_src = bsum + 1024;                    // E
    float* h1s = (float*)(csr_src + ((E + 63) & ~63));  // N*64
    float* h2 = h1s + (size_t)N * 64;              // N*64
    float* h3s = h1s;                              // reuse h1s (N*32)
    float* out = (float*)d_out;

    // 1) degrees -> dinv
    hipMemsetAsync(deg, 0, (size_t)N * 4, stream);
    deg_kernel<<<(E + 255) / 256, 256, 0, stream>>>(dst, E, deg);
    dinv_kernel<<<NB, 256, 0, stream>>>(deg, dinv, N);

    // 2) CSR: offs = exscan(deg); fill csr_src grouped by dst
    blocksum_kernel<<<NB, 256, 0, stream>>>(deg, N, bsum);
    scan_bsum_kernel<<<1, 1024, 0, stream>>>(bsum, NB);
    offsets_kernel<<<NB, 256, 0, stream>>>(deg, bsum, offs, N, E);
    copy_kernel<<<NB, 256, 0, stream>>>(offs, cursor, N);
    fill_kernel<<<(E + 255) / 256, 256, 0, stream>>>(src, dst, E, cursor, csr_src);

    // 3) h1s = (x @ W1) * dinv
    gemm_kernel<128, 64><<<4096, 256, 0, stream>>>(x, W1, dinv, h1s, N);

    // 4) h2 = relu(dinv*(gather h1s) + b1)
    gather_kernel<64, true><<<(N * 64 + 255) / 256, 256, 0, stream>>>(h1s, dinv, offs, csr_src, b1, h2, N);

    // 5) h3s = (h2 @ W2) * dinv
    gemm_kernel<64, 32><<<4096, 256, 0, stream>>>(h2, W2, dinv, h3s, N);

    // 6) out = dinv*(gather h3s) + b2
    gather_kernel<32, false><<<(N * 32 + 255) / 256, 256, 0, stream>>>(h3s, dinv, offs, csr_src, b2, out, N);
}